// Round 1
// baseline (6267.617 us; speedup 1.0000x reference)
//
#include <hip/hip_runtime.h>
#include <math.h>

#define B_ 16
#define T_ 64
#define C_ 64
#define W_ 256
#define H_ 128
#define CH_ 192   // C_ + H_
#define K_ 5

#define OUT_SEQ_ELEMS ((size_t)B_ * T_ * H_ * W_)            // 33,554,432
#define OUT_H_OFF     OUT_SEQ_ELEMS                          // final h [B,H,W]
#define OUT_C_OFF     (OUT_SEQ_ELEMS + (size_t)B_ * H_ * W_) // final c [B,H,W] (also running c state)

__device__ __forceinline__ float sigmoid_f(float x) {
    return 1.0f / (1.0f + __expf(-x));
}
__device__ __forceinline__ float tanh_f(float x) {
    // tanh(x) = 1 - 2/(exp(2x)+1); saturates correctly for large |x| with __expf
    return 1.0f - 2.0f / (__expf(2.0f * x) + 1.0f);
}

// One block per (hc, b). 128 threads; thread handles w0 = tid and w1 = tid+128.
// Weight accesses are wave-uniform -> scalar loads via constant cache.
__global__ __launch_bounds__(128)
void lstm_step(const float* __restrict__ x,    // [B,T,C,W]
               const float* __restrict__ Wc,   // [4H, CH, K]
               const float* __restrict__ bc,   // [4H]
               float* __restrict__ out,        // [B,T,H,W] ++ h[B,H,W] ++ c[B,H,W]
               int t)
{
    const int hc = blockIdx.x;   // 0..127
    const int b  = blockIdx.y;   // 0..15
    const int w0 = threadIdx.x;  // 0..127
    const int w1 = w0 + 128;

    float acc0[4], acc1[4];
#pragma unroll
    for (int g = 0; g < 4; ++g) {
        float bias = bc[g * H_ + hc];
        acc0[g] = bias;
        acc1[g] = bias;
    }

    const float* xbase = x   + (size_t)(b * T_ + t) * C_ * W_;       // x[b,t,:,:]
    const float* hbase = out + (size_t)(b * T_ + (t - 1)) * H_ * W_; // outputs[b,t-1,:,:] (valid if t>0)

    // ---- x contribution: weight input-channels [0, 64) ----
    for (int ci = 0; ci < C_; ++ci) {
        const float* in = xbase + ci * W_;
        float v0[K_], v1[K_];
#pragma unroll
        for (int k = 0; k < K_; ++k) {
            int p0 = w0 + k - 2;          // can be <0 only (w0<=127 so p0<=129<W_)
            int p1 = w1 + k - 2;          // can be >=W_ only (w1>=128 so p1>=126>=0)
            v0[k] = (p0 >= 0)  ? in[p0] : 0.0f;
            v1[k] = (p1 < W_)  ? in[p1] : 0.0f;
        }
#pragma unroll
        for (int g = 0; g < 4; ++g) {
            const float* wp = Wc + ((size_t)(g * H_ + hc) * CH_ + ci) * K_;
#pragma unroll
            for (int k = 0; k < K_; ++k) {
                acc0[g] = fmaf(wp[k], v0[k], acc0[g]);
                acc1[g] = fmaf(wp[k], v1[k], acc1[g]);
            }
        }
    }

    // ---- h contribution: weight input-channels [64, 192) ----
    if (t > 0) {
        for (int ci = 0; ci < H_; ++ci) {
            const float* in = hbase + ci * W_;
            float v0[K_], v1[K_];
#pragma unroll
            for (int k = 0; k < K_; ++k) {
                int p0 = w0 + k - 2;
                int p1 = w1 + k - 2;
                v0[k] = (p0 >= 0)  ? in[p0] : 0.0f;
                v1[k] = (p1 < W_)  ? in[p1] : 0.0f;
            }
#pragma unroll
            for (int g = 0; g < 4; ++g) {
                const float* wp = Wc + ((size_t)(g * H_ + hc) * CH_ + (C_ + ci)) * K_;
#pragma unroll
                for (int k = 0; k < K_; ++k) {
                    acc0[g] = fmaf(wp[k], v0[k], acc0[g]);
                    acc1[g] = fmaf(wp[k], v1[k], acc1[g]);
                }
            }
        }
    }

    // ---- LSTM gating ----
    const size_t cidx0 = OUT_C_OFF + (size_t)(b * H_ + hc) * W_ + w0;
    const size_t cidx1 = cidx0 + 128;
    float cp0 = (t > 0) ? out[cidx0] : 0.0f;
    float cp1 = (t > 0) ? out[cidx1] : 0.0f;

    float i0 = sigmoid_f(acc0[0]), f0 = sigmoid_f(acc0[1]);
    float o0 = sigmoid_f(acc0[2]), g0 = tanh_f(acc0[3]);
    float i1 = sigmoid_f(acc1[0]), f1 = sigmoid_f(acc1[1]);
    float o1 = sigmoid_f(acc1[2]), g1 = tanh_f(acc1[3]);

    float cn0 = f0 * cp0 + i0 * g0;
    float cn1 = f1 * cp1 + i1 * g1;
    float hn0 = o0 * tanh_f(cn0);
    float hn1 = o1 * tanh_f(cn1);

    out[cidx0] = cn0;   // running c state; at t==T-1 this IS the final c output
    out[cidx1] = cn1;

    const size_t hidx = ((size_t)(b * T_ + t) * H_ + hc) * W_ + w0;
    out[hidx]        = hn0;
    out[hidx + 128]  = hn1;

    if (t == T_ - 1) {  // final h output
        const size_t hf = OUT_H_OFF + (size_t)(b * H_ + hc) * W_ + w0;
        out[hf]       = hn0;
        out[hf + 128] = hn1;
    }
}

extern "C" void kernel_launch(void* const* d_in, const int* in_sizes, int n_in,
                              void* d_out, int out_size, void* d_ws, size_t ws_size,
                              hipStream_t stream)
{
    const float* x  = (const float*)d_in[0];
    const float* Wc = (const float*)d_in[1];
    const float* bc = (const float*)d_in[2];
    float* out = (float*)d_out;

    dim3 grid(H_, B_);
    for (int t = 0; t < T_; ++t) {
        lstm_step<<<grid, 128, 0, stream>>>(x, Wc, bc, out, t);
    }
}

// Round 2
// 1331.754 us; speedup vs baseline: 4.7063x; 4.7063x over previous
//
#include <hip/hip_runtime.h>
#include <hip/hip_bf16.h>
#include <math.h>

#define B_ 16
#define T_ 64
#define C_ 64
#define W_ 256
#define H_ 128
#define CH_ 192   // C_ + H_
#define K_ 5

#define OUT_SEQ_ELEMS ((size_t)B_ * T_ * H_ * W_)            // 33,554,432
#define OUT_H_OFF     OUT_SEQ_ELEMS                          // final h [B,H,W]
#define OUT_C_OFF     (OUT_SEQ_ELEMS + (size_t)B_ * H_ * W_) // final c (also running c state)

// ---- workspace layout (bytes) ----
#define WS_WF_OFF  0                              // Wfrag bf16: 960 frags * 64 lanes * 8 = 491520 el
#define WS_XT_OFF  (983040)                       // xT bf16 [B][T][W][C] = 16.7M el = 33554432 B
#define WS_HT_OFF  (WS_XT_OFF + 33554432)         // 2 x hT bf16 [B][W][H] = 524288 el each
#define HT_ELEMS   ((size_t)B_ * W_ * H_)

typedef __attribute__((ext_vector_type(8))) short bf16x8;
typedef __attribute__((ext_vector_type(4))) float f32x4;
typedef __attribute__((ext_vector_type(4))) unsigned int u32x4;

__device__ __forceinline__ float sigmoid_f(float x) {
    return 1.0f / (1.0f + __expf(-x));
}
__device__ __forceinline__ float tanh_f(float x) {
    return 1.0f - 2.0f / (__expf(2.0f * x) + 1.0f);
}

// ---------- prep: weights -> MFMA fragment-major bf16 ----------
// layout: frag f = ((ht*4 + g)*5 + ktap)*6 + chunk ; element [f][lane][j]
// value = Wc[g*128 + ht*16 + (lane&15)][chunk*32 + 8*(lane>>4) + j][ktap]
__global__ __launch_bounds__(256)
void prep_wfrag(const float* __restrict__ Wc, __hip_bfloat16* __restrict__ wf) {
    int idx = blockIdx.x * 256 + threadIdx.x;   // one per (frag,lane); 960*64 = 61440
    if (idx >= 960 * 64) return;
    int lane  = idx & 63;
    int f     = idx >> 6;
    int chunk = f % 6;
    int ktap  = (f / 6) % 5;
    int g     = (f / 30) % 4;
    int ht    = f / 120;
    int chan  = g * 128 + ht * 16 + (lane & 15);
    int ci0   = chunk * 32 + 8 * (lane >> 4);
    __hip_bfloat16 tmp[8];
#pragma unroll
    for (int j = 0; j < 8; ++j)
        tmp[j] = __float2bfloat16(Wc[((size_t)chan * CH_ + (ci0 + j)) * K_ + ktap]);
    *reinterpret_cast<u32x4*>(&wf[(size_t)idx * 8]) = *reinterpret_cast<const u32x4*>(tmp);
}

// ---------- prep: x [B,T,C,W] f32 -> xT [B,T,W,C] bf16 ----------
__global__ __launch_bounds__(256)
void prep_xt(const float* __restrict__ x, __hip_bfloat16* __restrict__ xt) {
    __shared__ float tile[64][65];
    int bt = blockIdx.x;            // b*T + t
    int w0 = blockIdx.y * 64;
    const float* src = x + (size_t)bt * C_ * W_ + w0;
#pragma unroll
    for (int i = 0; i < 16; ++i) {
        int idx = i * 256 + threadIdx.x;   // 4096 = 64ci x 64w
        int ci = idx >> 6, wr = idx & 63;
        tile[ci][wr] = src[(size_t)ci * W_ + wr];
    }
    __syncthreads();
    __hip_bfloat16* dst = xt + ((size_t)bt * W_ + w0) * C_;
#pragma unroll
    for (int i = 0; i < 8; ++i) {
        int idx = i * 256 + threadIdx.x;   // 2048, 2 ci each
        int wr = idx >> 5, cp = (idx & 31) * 2;
        __hip_bfloat16 a = __float2bfloat16(tile[cp][wr]);
        __hip_bfloat16 b = __float2bfloat16(tile[cp + 1][wr]);
        ushort2 v;
        v.x = *reinterpret_cast<unsigned short*>(&a);
        v.y = *reinterpret_cast<unsigned short*>(&b);
        *reinterpret_cast<ushort2*>(&dst[(size_t)wr * C_ + cp]) = v;
    }
}

// ---------- sequential step: MFMA conv + LSTM gating ----------
#define PITCH_B 384   // bytes per combT row (192 ci * 2B), XOR-swizzled
#define NROWS   132   // 128 positions + 4 halo

__global__ __launch_bounds__(256)
void lstm_step_mfma(const __hip_bfloat16* __restrict__ xt,
                    const __hip_bfloat16* __restrict__ wf,
                    const float* __restrict__ bc,
                    const __hip_bfloat16* __restrict__ ht_in,
                    __hip_bfloat16* __restrict__ ht_out,
                    float* __restrict__ out,
                    int t)
{
    __shared__ char lds[50688];          // combT 132*384 ; reused for gbuf(32K)+hbf(6K)
    const int ht   = blockIdx.x;         // 0..7  -> h-channels [ht*16, ht*16+16)
    const int wseg = blockIdx.y;         // 0..1  -> positions [wseg*128, +128)
    const int b    = blockIdx.z;         // 0..15
    const int tid  = threadIdx.x;
    const int lane = tid & 63;
    const int g    = tid >> 6;           // wave id == gate (i,f,o,g)
    const int l15  = lane & 15;
    const int lg   = lane >> 4;

    // ---- stage combT tile into LDS (bf16, XOR swizzle on 16B chunks) ----
    const int wbase = wseg * 128 - 2;
    const __hip_bfloat16* xrow = xt + ((size_t)(b * T_ + t) * W_) * C_;
    const __hip_bfloat16* hrow = ht_in + (size_t)b * W_ * H_;
    const int nch = (t > 0) ? 24 : 8;    // 16B chunks per row (x: 8, h: 16)
    for (int idx = tid; idx < NROWS * 24; idx += 256) {
        int wrel = idx / nch;
        int c16  = idx % nch;
        if (wrel >= NROWS) break;
        int w = wbase + wrel;
        u32x4 v = {0u, 0u, 0u, 0u};
        if (w >= 0 && w < W_) {
            if (c16 < 8) v = *reinterpret_cast<const u32x4*>(xrow + (size_t)w * C_ + c16 * 8);
            else         v = *reinterpret_cast<const u32x4*>(hrow + (size_t)w * H_ + (c16 - 8) * 8);
        }
        int byteoff = wrel * PITCH_B + ((c16 * 16) ^ ((wrel & 7) << 4));
        *reinterpret_cast<u32x4*>(lds + byteoff) = v;
    }
    __syncthreads();

    // ---- accumulators init with bias ----
    f32x4 acc[8];
    {
        int chanbase = g * 128 + ht * 16 + (lg << 2);
        float b0 = bc[chanbase], b1 = bc[chanbase + 1], b2 = bc[chanbase + 2], b3 = bc[chanbase + 3];
#pragma unroll
        for (int nf = 0; nf < 8; ++nf) { acc[nf][0] = b0; acc[nf][1] = b1; acc[nf][2] = b2; acc[nf][3] = b3; }
    }

    // ---- MFMA K-loop: chunks (32 ci) x 5 taps x 8 n-frags ----
    const int cend = (t > 0) ? 6 : 2;
    const __hip_bfloat16* wfbase = wf + (size_t)(ht * 4 + g) * 30 * 512 + (size_t)lane * 8;
    const int cib = 16 * lg;             // lane's ci byte offset within chunk

    for (int c = 0; c < cend; ++c) {
        for (int k = 0; k < K_; ++k) {
            bf16x8 afrag = *reinterpret_cast<const bf16x8*>(wfbase + (size_t)(k * 6 + c) * 512);
#pragma unroll
            for (int nf = 0; nf < 8; ++nf) {
                int wrel = nf * 16 + l15 + k;
                int byteoff = wrel * PITCH_B + ((c * 64 + cib) ^ ((wrel & 7) << 4));
                bf16x8 bfrag = *reinterpret_cast<const bf16x8*>(lds + byteoff);
                acc[nf] = __builtin_amdgcn_mfma_f32_16x16x32_bf16(afrag, bfrag, acc[nf], 0, 0, 0);
            }
        }
    }

    // ---- exchange gates through LDS ----
    __syncthreads();                                   // combT dead from here
    float* gbuf = reinterpret_cast<float*>(lds);       // [4][16][128] f32 = 32 KB
    {
        int rowb = lg << 2;
#pragma unroll
        for (int nf = 0; nf < 8; ++nf)
#pragma unroll
            for (int r = 0; r < 4; ++r)
                gbuf[(g * 16 + rowb + r) * 128 + nf * 16 + l15] = acc[nf][r];
    }
    __syncthreads();

    // ---- gating + writes ----
    __hip_bfloat16* hbf = reinterpret_cast<__hip_bfloat16*>(lds + 32768); // [128 pos][pitch 24 bf16]
    const size_t cbase = OUT_C_OFF + ((size_t)b * H_ + ht * 16) * W_ + wseg * 128;
    float* hw = out + ((size_t)(b * T_ + t) * H_ + ht * 16) * W_ + wseg * 128;
    float* hf = out + OUT_H_OFF + ((size_t)b * H_ + ht * 16) * W_ + wseg * 128;

#pragma unroll
    for (int i = 0; i < 8; ++i) {
        int idx  = i * 256 + tid;       // 2048 = 16 chan x 128 pos
        int chan = idx >> 7;
        int pos  = idx & 127;
        float vi = gbuf[(0 * 16 + chan) * 128 + pos];
        float vf = gbuf[(1 * 16 + chan) * 128 + pos];
        float vo = gbuf[(2 * 16 + chan) * 128 + pos];
        float vg = gbuf[(3 * 16 + chan) * 128 + pos];
        float ii = sigmoid_f(vi), ff = sigmoid_f(vf), oo = sigmoid_f(vo), gg = tanh_f(vg);
        float cprev = (t > 0) ? out[cbase + (size_t)chan * W_ + pos] : 0.0f;
        float cn = ff * cprev + ii * gg;
        float hn = oo * tanh_f(cn);
        out[cbase + (size_t)chan * W_ + pos] = cn;
        hw[(size_t)chan * W_ + pos] = hn;
        if (t == T_ - 1) hf[(size_t)chan * W_ + pos] = hn;
        hbf[pos * 24 + chan] = __float2bfloat16(hn);
    }
    __syncthreads();

    // ---- write hT (bf16, [b][w][ci]) for next step ----
    {
        int w = tid >> 1, grp = tid & 1;   // 128 w x 2 groups of 8 ci
        u32x4 v = *reinterpret_cast<const u32x4*>(lds + 32768 + w * 48 + grp * 16);
        *reinterpret_cast<u32x4*>(ht_out + ((size_t)b * W_ + wseg * 128 + w) * H_ + ht * 16 + grp * 8) = v;
    }
}

extern "C" void kernel_launch(void* const* d_in, const int* in_sizes, int n_in,
                              void* d_out, int out_size, void* d_ws, size_t ws_size,
                              hipStream_t stream)
{
    const float* x  = (const float*)d_in[0];
    const float* Wc = (const float*)d_in[1];
    const float* bc = (const float*)d_in[2];
    float* out = (float*)d_out;
    char*  ws  = (char*)d_ws;

    __hip_bfloat16* wf  = (__hip_bfloat16*)(ws + WS_WF_OFF);
    __hip_bfloat16* xt  = (__hip_bfloat16*)(ws + WS_XT_OFF);
    __hip_bfloat16* hb0 = (__hip_bfloat16*)(ws + WS_HT_OFF);
    __hip_bfloat16* hb1 = hb0 + HT_ELEMS;

    prep_wfrag<<<240, 256, 0, stream>>>(Wc, wf);
    prep_xt<<<dim3(B_ * T_, 4), 256, 0, stream>>>(x, xt);

    for (int t = 0; t < T_; ++t) {
        __hip_bfloat16* hin  = (t & 1) ? hb1 : hb0;
        __hip_bfloat16* hout = (t & 1) ? hb0 : hb1;
        lstm_step_mfma<<<dim3(8, 2, B_), 256, 0, stream>>>(xt, wf, bc, hin, hout, out, t);
    }
}